// Round 5
// baseline (148.439 us; speedup 1.0000x reference)
//
#include <hip/hip_runtime.h>

// ---------------------------------------------------------------------------
// CVX_Reasoning_Engine — Round 5: ILP (grid pins occupancy at 8 waves/CU).
//   * explicit 1-deep register prefetch of fragment-ordered B weights
//   * L1: z staged in registers as two 256-wide halves -> 5 barriers (was 17)
//   * small layers (L3/L4): all B fragments preloaded to registers
//   * launch_bounds(256,2) for VGPR headroom (grid gives 2 blocks/CU anyway)
// ---------------------------------------------------------------------------

#define MROWS 16384

typedef __attribute__((ext_vector_type(8))) short bf16x8;   // 8 bf16 = 4 VGPRs
typedef __attribute__((ext_vector_type(4))) float floatx4;

__device__ __forceinline__ unsigned short f2bf(float x) {
    union { float f; unsigned u; } c; c.f = x;
    unsigned r = c.u + 0x7fffu + ((c.u >> 16) & 1u);   // RNE
    return (unsigned short)(r >> 16);
}
__device__ __forceinline__ float bf2f(unsigned short b) {
    union { unsigned u; float f; } c; c.u = ((unsigned)b) << 16;
    return c.f;
}

// ---- pack W (KxN fp32) -> fragment-ordered bf16 ----------------------------
// T[((ntile*KS + ks)*64 + lane)*8 + e] = W[k][n],  n = ntile*16 + (lane&15),
// k = ks*32 + (lane>>4)*8 + e.  Reads coalesced (idx = k*N + n, n fastest).
__global__ __launch_bounds__(256) void pack_wt(
    const float* __restrict__ W1, unsigned short* __restrict__ T1,
    const float* __restrict__ W2, unsigned short* __restrict__ T2,
    const float* __restrict__ W3, unsigned short* __restrict__ T3,
    const float* __restrict__ W4, unsigned short* __restrict__ T4)
{
    const float* W; unsigned short* T; int Kreal, KS, nshift;
    switch (blockIdx.y) {
        case 0:  W = W1; T = T1; Kreal = 516; KS = 17; nshift = 9; break;
        case 1:  W = W2; T = T2; Kreal = 512; KS = 16; nshift = 8; break;
        case 2:  W = W3; T = T3; Kreal = 256; KS = 8;  nshift = 7; break;
        default: W = W4; T = T4; Kreal = 128; KS = 4;  nshift = 6; break;
    }
    const int N = 1 << nshift;
    const int idx = blockIdx.x * 256 + threadIdx.x;   // k*N + n over padded K
    if (idx >= N * KS * 32) return;
    const int k = idx >> nshift;
    const int n = idx & (N - 1);
    const unsigned short v = (k < Kreal) ? f2bf(W[idx]) : (unsigned short)0;
    const int ntile = n >> 4, m_l = n & 15;
    const int ks = k >> 5, quad = (k >> 3) & 3, e = k & 7;
    T[(size_t)(((ntile * KS + ks) * 64) + quad * 16 + m_l) * 8 + e] = v;
}

// ---- LDS layout (ushort element offsets) -----------------------------------
// h1 32x520 @0 (h3 overlays @0 later); misc @16640 = z-stage 32x264, then
// h2 32x264, then h4 32x72.  Total 50,176 B.
#define OFF_H1   0
#define OFF_MISC 16640
#define OFF_H3   0
#define LDS_TOT  25088
#define LD_STG   264
#define LD_H1    520
#define LD_H2    264
#define LD_H3    136
#define LD_H4    72

// generic MFMA layer: C[32xN] = lrelu(A[32xK] @ W^T + bias)
// Wt fragment-ordered; 4 waves split N; wave tile 32 x (NF*16).
// NF*KSTEPS<=16: preload all B to regs.  Else: rolling 1-deep ks prefetch.
template<int NF, int KSTEPS>
__device__ __forceinline__ void layer_gemm(
    unsigned short* lds, int offA, int lda, int offC, int ldc,
    const unsigned short* __restrict__ Wt,
    const float* __restrict__ bias, int wid, int lane)
{
    const int m_l = lane & 15, quad = lane >> 4;
    const unsigned short* __restrict__ Wl =
        Wt + ((size_t)(wid * NF) * KSTEPS * 64 + lane) * 8;
    floatx4 acc[2][NF];
    #pragma unroll
    for (int i = 0; i < 2; ++i)
        #pragma unroll
        for (int j = 0; j < NF; ++j)
            acc[i][j] = (floatx4){0.f, 0.f, 0.f, 0.f};

    if constexpr (NF * KSTEPS <= 16) {
        bf16x8 b[NF * KSTEPS];
        #pragma unroll
        for (int t = 0; t < NF * KSTEPS; ++t)
            b[t] = *(const bf16x8*)(Wl + (size_t)t * 512);
        #pragma unroll
        for (int ks = 0; ks < KSTEPS; ++ks) {
            const bf16x8 a0 = *(const bf16x8*)&lds[offA + (m_l     ) * lda + ks*32 + quad*8];
            const bf16x8 a1 = *(const bf16x8*)&lds[offA + (m_l + 16) * lda + ks*32 + quad*8];
            #pragma unroll
            for (int j = 0; j < NF; ++j) {
                acc[0][j] = __builtin_amdgcn_mfma_f32_16x16x32_bf16(a0, b[j*KSTEPS+ks], acc[0][j], 0, 0, 0);
                acc[1][j] = __builtin_amdgcn_mfma_f32_16x16x32_bf16(a1, b[j*KSTEPS+ks], acc[1][j], 0, 0, 0);
            }
        }
    } else {
        bf16x8 bc[NF], bn[NF];
        #pragma unroll
        for (int j = 0; j < NF; ++j)
            bc[j] = *(const bf16x8*)(Wl + (size_t)(j * KSTEPS) * 512);
        #pragma unroll
        for (int ks = 0; ks < KSTEPS; ++ks) {
            if (ks + 1 < KSTEPS) {
                #pragma unroll
                for (int j = 0; j < NF; ++j)
                    bn[j] = *(const bf16x8*)(Wl + (size_t)(j * KSTEPS + ks + 1) * 512);
            }
            const bf16x8 a0 = *(const bf16x8*)&lds[offA + (m_l     ) * lda + ks*32 + quad*8];
            const bf16x8 a1 = *(const bf16x8*)&lds[offA + (m_l + 16) * lda + ks*32 + quad*8];
            #pragma unroll
            for (int j = 0; j < NF; ++j) {
                acc[0][j] = __builtin_amdgcn_mfma_f32_16x16x32_bf16(a0, bc[j], acc[0][j], 0, 0, 0);
                acc[1][j] = __builtin_amdgcn_mfma_f32_16x16x32_bf16(a1, bc[j], acc[1][j], 0, 0, 0);
            }
            if (ks + 1 < KSTEPS) {
                #pragma unroll
                for (int j = 0; j < NF; ++j) bc[j] = bn[j];
            }
        }
    }
    // epilogue: bias + lrelu -> bf16 LDS. C/D: col=lane&15, row=quad*4+r.
    #pragma unroll
    for (int j = 0; j < NF; ++j) {
        const int col = wid * (NF * 16) + j * 16 + m_l;
        const float bv = bias[col];
        #pragma unroll
        for (int i = 0; i < 2; ++i)
            #pragma unroll
            for (int r = 0; r < 4; ++r) {
                float v = acc[i][j][r] + bv;
                v = v > 0.f ? v : 0.2f * v;
                lds[offC + (i*16 + quad*4 + r) * ldc + col] = f2bf(v);
            }
    }
}

__global__ __launch_bounds__(256, 2) void fused_mlp_qp(
    const float* __restrict__ z, const float* __restrict__ bounds,
    const unsigned short* __restrict__ Wt1, const float* __restrict__ c1,
    const unsigned short* __restrict__ Wt2, const float* __restrict__ c2,
    const unsigned short* __restrict__ Wt3, const float* __restrict__ c3,
    const unsigned short* __restrict__ Wt4, const float* __restrict__ c4,
    const float* __restrict__ W5, const float* __restrict__ c5,
    float* __restrict__ out)
{
    __shared__ unsigned short lds[LDS_TOT];
    const int tid  = threadIdx.x;
    const int wid  = tid >> 6, lane = tid & 63;
    const int m_l  = lane & 15, quad = lane >> 4;
    const int bm   = blockIdx.x * 32;

    const float4 bnd = *(const float4*)bounds;     // early, reused in tail + QP

    // ---------------- Layer 1: K=544, z in two register-staged halves -------
    floatx4 acc1[2][8];
    #pragma unroll
    for (int i = 0; i < 2; ++i)
        #pragma unroll
        for (int j = 0; j < 8; ++j)
            acc1[i][j] = (floatx4){0.f, 0.f, 0.f, 0.f};

    const int srow = tid >> 3;            // 0..31
    const int sc4  = (tid & 7) * 4;       // 0..28
    const float* __restrict__ zb = z + (size_t)(bm + srow) * 512 + sc4;
    const unsigned short* __restrict__ W1l = Wt1 + ((size_t)(wid * 8) * 17 * 64 + lane) * 8;

    float4 zr[8];
    #pragma unroll
    for (int i = 0; i < 8; ++i) zr[i] = *(const float4*)(zb + i * 32);
    #pragma unroll
    for (int i = 0; i < 8; ++i) {
        unsigned short t4[4] = {f2bf(zr[i].x), f2bf(zr[i].y), f2bf(zr[i].z), f2bf(zr[i].w)};
        *(uint2*)&lds[OFF_MISC + srow * LD_STG + sc4 + i * 32] = *(uint2*)t4;
    }
    bf16x8 bc[8], bn[8];
    #pragma unroll
    for (int j = 0; j < 8; ++j)
        bc[j] = *(const bf16x8*)(W1l + (size_t)(j * 17) * 512);
    #pragma unroll
    for (int i = 0; i < 8; ++i) zr[i] = *(const float4*)(zb + 256 + i * 32);  // half1 in flight
    __syncthreads();

    // half0: ks 0..7 (prefetch rolls into ks=8, half1's first fragment)
    #pragma unroll
    for (int ks = 0; ks < 8; ++ks) {
        #pragma unroll
        for (int j = 0; j < 8; ++j)
            bn[j] = *(const bf16x8*)(W1l + (size_t)(j * 17 + ks + 1) * 512);
        const bf16x8 a0 = *(const bf16x8*)&lds[OFF_MISC + (m_l     ) * LD_STG + ks*32 + quad*8];
        const bf16x8 a1 = *(const bf16x8*)&lds[OFF_MISC + (m_l + 16) * LD_STG + ks*32 + quad*8];
        #pragma unroll
        for (int j = 0; j < 8; ++j) {
            acc1[0][j] = __builtin_amdgcn_mfma_f32_16x16x32_bf16(a0, bc[j], acc1[0][j], 0, 0, 0);
            acc1[1][j] = __builtin_amdgcn_mfma_f32_16x16x32_bf16(a1, bc[j], acc1[1][j], 0, 0, 0);
        }
        #pragma unroll
        for (int j = 0; j < 8; ++j) bc[j] = bn[j];
    }
    __syncthreads();
    #pragma unroll
    for (int i = 0; i < 8; ++i) {
        unsigned short t4[4] = {f2bf(zr[i].x), f2bf(zr[i].y), f2bf(zr[i].z), f2bf(zr[i].w)};
        *(uint2*)&lds[OFF_MISC + srow * LD_STG + sc4 + i * 32] = *(uint2*)t4;
    }
    __syncthreads();

    // half1: ks 8..15 (prefetch rolls into ks=16, the bounds tail)
    #pragma unroll
    for (int ks = 8; ks < 16; ++ks) {
        #pragma unroll
        for (int j = 0; j < 8; ++j)
            bn[j] = *(const bf16x8*)(W1l + (size_t)(j * 17 + ks + 1) * 512);
        const bf16x8 a0 = *(const bf16x8*)&lds[OFF_MISC + (m_l     ) * LD_STG + (ks-8)*32 + quad*8];
        const bf16x8 a1 = *(const bf16x8*)&lds[OFF_MISC + (m_l + 16) * LD_STG + (ks-8)*32 + quad*8];
        #pragma unroll
        for (int j = 0; j < 8; ++j) {
            acc1[0][j] = __builtin_amdgcn_mfma_f32_16x16x32_bf16(a0, bc[j], acc1[0][j], 0, 0, 0);
            acc1[1][j] = __builtin_amdgcn_mfma_f32_16x16x32_bf16(a1, bc[j], acc1[1][j], 0, 0, 0);
        }
        #pragma unroll
        for (int j = 0; j < 8; ++j) bc[j] = bn[j];
    }
    __syncthreads();
    // tail stage: k 512..543 = bounds then zeros
    {
        const int frow = tid >> 3;
        const int fkl  = (tid & 7) * 4;
        unsigned short t4[4] = {0, 0, 0, 0};
        if (fkl == 0) { t4[0] = f2bf(bnd.x); t4[1] = f2bf(bnd.y);
                        t4[2] = f2bf(bnd.z); t4[3] = f2bf(bnd.w); }
        *(uint2*)&lds[OFF_MISC + frow * LD_STG + fkl] = *(uint2*)t4;
    }
    __syncthreads();
    // tail: ks 16 (bc holds fragment 17j+16 from the last prefetch)
    {
        const bf16x8 a0 = *(const bf16x8*)&lds[OFF_MISC + (m_l     ) * LD_STG + quad*8];
        const bf16x8 a1 = *(const bf16x8*)&lds[OFF_MISC + (m_l + 16) * LD_STG + quad*8];
        #pragma unroll
        for (int j = 0; j < 8; ++j) {
            acc1[0][j] = __builtin_amdgcn_mfma_f32_16x16x32_bf16(a0, bc[j], acc1[0][j], 0, 0, 0);
            acc1[1][j] = __builtin_amdgcn_mfma_f32_16x16x32_bf16(a1, bc[j], acc1[1][j], 0, 0, 0);
        }
    }
    // L1 epilogue -> h1
    #pragma unroll
    for (int j = 0; j < 8; ++j) {
        const int col = wid*128 + j*16 + m_l;
        const float bv = c1[col];
        #pragma unroll
        for (int i = 0; i < 2; ++i)
            #pragma unroll
            for (int r = 0; r < 4; ++r) {
                float v = acc1[i][j][r] + bv;
                v = v > 0.f ? v : 0.2f * v;
                lds[OFF_H1 + (i*16 + quad*4 + r) * LD_H1 + col] = f2bf(v);
            }
    }
    __syncthreads();

    // ---------------- Layers 2-4 (LDS-resident) -----------------------------
    layer_gemm<4,16>(lds, OFF_H1,   LD_H1, OFF_MISC, LD_H2, Wt2, c2, wid, lane);
    __syncthreads();
    layer_gemm<2,8 >(lds, OFF_MISC, LD_H2, OFF_H3,   LD_H3, Wt3, c3, wid, lane);
    __syncthreads();
    layer_gemm<1,4 >(lds, OFF_H3,   LD_H3, OFF_MISC, LD_H4, Wt4, c4, wid, lane);
    __syncthreads();

    // ---------------- Layer 5 (64->256 fp32) + QP ---------------------------
    const float4 cc = ((const float4*)c5)[lane];
    float ax[8], ay[8], aw[8], ah[8];
    #pragma unroll
    for (int r = 0; r < 8; ++r) { ax[r] = cc.x; ay[r] = cc.y; aw[r] = cc.z; ah[r] = cc.w; }
    const float4* __restrict__ W5v = (const float4*)W5;   // [k][64 objs]
    const int rbase = wid * 8;

    float4 wv[4], wn[4];
    #pragma unroll
    for (int kk = 0; kk < 4; ++kk) wv[kk] = W5v[(size_t)kk * 64 + lane];

    for (int k4 = 0; k4 < 64; k4 += 4) {
        if (k4 + 4 < 64) {
            #pragma unroll
            for (int kk = 0; kk < 4; ++kk)
                wn[kk] = W5v[(size_t)(k4 + 4 + kk) * 64 + lane];
        }
        unsigned short hs[8][4];
        #pragma unroll
        for (int r = 0; r < 8; ++r) {
            const ushort4 t = *(const ushort4*)&lds[OFF_MISC + (rbase + r) * LD_H4 + k4];
            hs[r][0] = t.x; hs[r][1] = t.y; hs[r][2] = t.z; hs[r][3] = t.w;
        }
        #pragma unroll
        for (int kk = 0; kk < 4; ++kk) {
            #pragma unroll
            for (int r = 0; r < 8; ++r) {
                const float h = bf2f(hs[r][kk]);
                ax[r] = fmaf(h, wv[kk].x, ax[r]);
                ay[r] = fmaf(h, wv[kk].y, ay[r]);
                aw[r] = fmaf(h, wv[kk].z, aw[r]);
                ah[r] = fmaf(h, wv[kk].w, ah[r]);
            }
        }
        if (k4 + 4 < 64) {
            #pragma unroll
            for (int kk = 0; kk < 4; ++kk) wv[kk] = wn[kk];
        }
    }

    const float b0 = bnd.x, b1 = bnd.y, b2 = bnd.z, b3 = bnd.w;
    #pragma unroll
    for (int r = 0; r < 8; ++r) {
        float xs, wo, ys, ho;
        {
            const float px = ax[r], pw = aw[r];
            const float x0 = fmaxf(px, b0);
            const float g0 = fmaxf(pw, 1.0f);
            const float t  = 0.5f * (b2 - px - pw);
            const float xl = fminf(fmaxf(px + t, b0), b2 - 1.0f);
            const bool over = (x0 + g0) > b2;
            const float x = over ? xl : x0;
            const float g = over ? (b2 - xl) : g0;
            xs = x; wo = x + g;
        }
        {
            const float py = ay[r], ph = ah[r];
            const float x0 = fmaxf(py, b1);
            const float g0 = fmaxf(ph, 1.0f);
            const float t  = 0.5f * (b3 - py - ph);
            const float xl = fminf(fmaxf(py + t, b1), b3 - 1.0f);
            const bool over = (x0 + g0) > b3;
            const float x = over ? xl : x0;
            const float g = over ? (b3 - xl) : g0;
            ys = x; ho = x + g;
        }
        float4 o; o.x = xs; o.y = ys; o.z = wo; o.w = ho;
        ((float4*)out)[(size_t)(bm + rbase + r) * 64 + lane] = o;
    }
}

extern "C" void kernel_launch(void* const* d_in, const int* in_sizes, int n_in,
                              void* d_out, int out_size, void* d_ws, size_t ws_size,
                              hipStream_t stream) {
    const float* z      = (const float*)d_in[0];
    const float* bounds = (const float*)d_in[1];
    const float* W1 = (const float*)d_in[2];
    const float* c1 = (const float*)d_in[3];
    const float* W2 = (const float*)d_in[4];
    const float* c2 = (const float*)d_in[5];
    const float* W3 = (const float*)d_in[6];
    const float* c3 = (const float*)d_in[7];
    const float* W4 = (const float*)d_in[8];
    const float* c4 = (const float*)d_in[9];
    const float* W5 = (const float*)d_in[10];
    const float* c5 = (const float*)d_in[11];
    float* out = (float*)d_out;

    unsigned short* ws  = (unsigned short*)d_ws;
    unsigned short* Wt1 = ws;               // 512x544 = 278528
    unsigned short* Wt2 = Wt1 + 278528;     // 256x512 = 131072
    unsigned short* Wt3 = Wt2 + 131072;     // 128x256 = 32768
    unsigned short* Wt4 = Wt3 + 32768;      //  64x128 =  8192

    pack_wt<<<dim3(1088, 4), 256, 0, stream>>>(W1, Wt1, W2, Wt2, W3, Wt3, W4, Wt4);
    fused_mlp_qp<<<dim3(MROWS / 32), 256, 0, stream>>>(
        z, bounds, Wt1, c1, Wt2, c2, Wt3, c3, Wt4, c4, W5, c5, out);
}

// Round 6
// 140.330 us; speedup vs baseline: 1.0578x; 1.0578x over previous
//
#include <hip/hip_runtime.h>

// ---------------------------------------------------------------------------
// CVX_Reasoning_Engine — Round 6: R4 structure, 64 rows/block (8 waves).
//   R5's manual prefetch/z-register staging REVERTED (compiler sank the
//   prefetches; VGPR=88 proved it). One change vs R4: blocks cover 64 rows
//   with 2m x 4n waves -> L2 weight traffic halves (m-twin waves share B
//   fragments via L1). Per-wave code identical to R4.
// ---------------------------------------------------------------------------

#define MROWS 16384

typedef __attribute__((ext_vector_type(8))) short bf16x8;   // 8 bf16 = 4 VGPRs
typedef __attribute__((ext_vector_type(4))) float floatx4;

__device__ __forceinline__ unsigned short f2bf(float x) {
    union { float f; unsigned u; } c; c.f = x;
    unsigned r = c.u + 0x7fffu + ((c.u >> 16) & 1u);   // RNE
    return (unsigned short)(r >> 16);
}
__device__ __forceinline__ float bf2f(unsigned short b) {
    union { unsigned u; float f; } c; c.u = ((unsigned)b) << 16;
    return c.f;
}

// ---- pack W (KxN fp32) -> fragment-ordered bf16 ----------------------------
// T[((ntile*KS + ks)*64 + lane)*8 + e] = W[k][n],  n = ntile*16 + (lane&15),
// k = ks*32 + (lane>>4)*8 + e.  Reads coalesced (idx = k*N + n, n fastest).
__global__ __launch_bounds__(256) void pack_wt(
    const float* __restrict__ W1, unsigned short* __restrict__ T1,
    const float* __restrict__ W2, unsigned short* __restrict__ T2,
    const float* __restrict__ W3, unsigned short* __restrict__ T3,
    const float* __restrict__ W4, unsigned short* __restrict__ T4)
{
    const float* W; unsigned short* T; int Kreal, KS, nshift;
    switch (blockIdx.y) {
        case 0:  W = W1; T = T1; Kreal = 516; KS = 17; nshift = 9; break;
        case 1:  W = W2; T = T2; Kreal = 512; KS = 16; nshift = 8; break;
        case 2:  W = W3; T = T3; Kreal = 256; KS = 8;  nshift = 7; break;
        default: W = W4; T = T4; Kreal = 128; KS = 4;  nshift = 6; break;
    }
    const int N = 1 << nshift;
    const int idx = blockIdx.x * 256 + threadIdx.x;   // k*N + n over padded K
    if (idx >= N * KS * 32) return;
    const int k = idx >> nshift;
    const int n = idx & (N - 1);
    const unsigned short v = (k < Kreal) ? f2bf(W[idx]) : (unsigned short)0;
    const int ntile = n >> 4, m_l = n & 15;
    const int ks = k >> 5, quad = (k >> 3) & 3, e = k & 7;
    T[(size_t)(((ntile * KS + ks) * 64) + quad * 16 + m_l) * 8 + e] = v;
}

// ---- LDS layout (ushort element offsets), 64-row block ----------------------
// h1 64x520 @0 (h3 64x136 overlays @0 after L2);
// misc @33280 = z-stage 2x64x72 (L1 only), then h2 64x264, then h4 64x72.
// Total 50,176 ushort = 100,352 B -> 1 block/CU.
#define OFF_H1   0
#define OFF_MISC 33280
#define OFF_H3   0
#define LDS_TOT  50176
#define LD_STG   72
#define STG_BUF  4608      /* 64*72 */
#define LD_H1    520
#define LD_H2    264
#define LD_H3    136
#define LD_H4    72

// generic MFMA layer: C[mrow..mrow+32, :] = lrelu(A @ W^T + bias) for this
// wave's n-slice. Wt fragment-ordered. Simple loop body (R4-style): the
// compiler's own vmcnt scheduling beat manual prefetch (R5 post-mortem).
template<int NF, int KSTEPS>
__device__ __forceinline__ void layer_gemm(
    unsigned short* lds, int offA, int lda, int offC, int ldc,
    const unsigned short* __restrict__ Wt,
    const float* __restrict__ bias, int wn, int mrow, int lane)
{
    const int m_l = lane & 15, quad = lane >> 4;
    const unsigned short* __restrict__ Wl =
        Wt + ((size_t)(wn * NF) * KSTEPS * 64 + lane) * 8;
    floatx4 acc[2][NF];
    #pragma unroll
    for (int i = 0; i < 2; ++i)
        #pragma unroll
        for (int j = 0; j < NF; ++j)
            acc[i][j] = (floatx4){0.f, 0.f, 0.f, 0.f};

    #pragma unroll
    for (int ks = 0; ks < KSTEPS; ++ks) {
        const bf16x8 a0 = *(const bf16x8*)&lds[offA + (mrow + m_l     ) * lda + ks*32 + quad*8];
        const bf16x8 a1 = *(const bf16x8*)&lds[offA + (mrow + m_l + 16) * lda + ks*32 + quad*8];
        #pragma unroll
        for (int j = 0; j < NF; ++j) {
            const bf16x8 b = *(const bf16x8*)(Wl + (size_t)(j * KSTEPS + ks) * 512);
            acc[0][j] = __builtin_amdgcn_mfma_f32_16x16x32_bf16(a0, b, acc[0][j], 0, 0, 0);
            acc[1][j] = __builtin_amdgcn_mfma_f32_16x16x32_bf16(a1, b, acc[1][j], 0, 0, 0);
        }
    }
    // epilogue: bias + lrelu -> bf16 LDS. C/D: col=lane&15, row=quad*4+r.
    #pragma unroll
    for (int j = 0; j < NF; ++j) {
        const int col = wn * (NF * 16) + j * 16 + m_l;
        const float bv = bias[col];
        #pragma unroll
        for (int i = 0; i < 2; ++i)
            #pragma unroll
            for (int r = 0; r < 4; ++r) {
                float v = acc[i][j][r] + bv;
                v = v > 0.f ? v : 0.2f * v;
                lds[offC + (mrow + i*16 + quad*4 + r) * ldc + col] = f2bf(v);
            }
    }
}

__global__ __launch_bounds__(512, 2) void fused_mlp_qp(
    const float* __restrict__ z, const float* __restrict__ bounds,
    const unsigned short* __restrict__ Wt1, const float* __restrict__ c1,
    const unsigned short* __restrict__ Wt2, const float* __restrict__ c2,
    const unsigned short* __restrict__ Wt3, const float* __restrict__ c3,
    const unsigned short* __restrict__ Wt4, const float* __restrict__ c4,
    const float* __restrict__ W5, const float* __restrict__ c5,
    float* __restrict__ out)
{
    __shared__ unsigned short lds[LDS_TOT];
    const int tid  = threadIdx.x;
    const int wid  = tid >> 6, lane = tid & 63;
    const int wm   = wid >> 2, wn = wid & 3;     // 2m x 4n wave grid
    const int mrow = wm * 32;
    const int m_l  = lane & 15, quad = lane >> 4;
    const int bm   = blockIdx.x * 64;

    // ---------------- Layer 1: K=544 streamed in 64-wide chunks -------------
    floatx4 acc1[2][8];
    #pragma unroll
    for (int i = 0; i < 2; ++i)
        #pragma unroll
        for (int j = 0; j < 8; ++j)
            acc1[i][j] = (floatx4){0.f, 0.f, 0.f, 0.f};

    const int srow = tid >> 3;          // 0..63
    const int skl  = (tid & 7) * 8;     // 0..56
    const float* __restrict__ zrow = z + (size_t)(bm + srow) * 512 + skl;
    // Wt1 fragment base for this wave's n-slice (8 n-tiles, KS=17)
    const unsigned short* __restrict__ W1l = Wt1 + ((size_t)(wn * 8) * 17 * 64 + lane) * 8;

    // stage chunk 0 into buf0
    {
        const float4 p0 = *(const float4*)(zrow + 0);
        const float4 p1 = *(const float4*)(zrow + 4);
        unsigned short t[8] = {f2bf(p0.x), f2bf(p0.y), f2bf(p0.z), f2bf(p0.w),
                               f2bf(p1.x), f2bf(p1.y), f2bf(p1.z), f2bf(p1.w)};
        *(uint4*)&lds[OFF_MISC + srow * LD_STG + skl] = *(uint4*)t;
    }

    for (int c = 0; c < 8; ++c) {
        float4 q0 = {0.f,0.f,0.f,0.f}, q1 = {0.f,0.f,0.f,0.f};
        if (c + 1 < 8) {                       // prefetch next chunk (HBM in flight)
            q0 = *(const float4*)(zrow + (c + 1) * 64);
            q1 = *(const float4*)(zrow + (c + 1) * 64 + 4);
        }
        __syncthreads();                       // stage[buf c] ready
        const int off = OFF_MISC + (c & 1) * STG_BUF;
        #pragma unroll
        for (int ks = 0; ks < 2; ++ks) {
            const bf16x8 a0 = *(const bf16x8*)&lds[off + (mrow + m_l     ) * LD_STG + ks*32 + quad*8];
            const bf16x8 a1 = *(const bf16x8*)&lds[off + (mrow + m_l + 16) * LD_STG + ks*32 + quad*8];
            #pragma unroll
            for (int j = 0; j < 8; ++j) {
                const bf16x8 b = *(const bf16x8*)(W1l + (size_t)(j * 17 + c*2 + ks) * 512);
                acc1[0][j] = __builtin_amdgcn_mfma_f32_16x16x32_bf16(a0, b, acc1[0][j], 0, 0, 0);
                acc1[1][j] = __builtin_amdgcn_mfma_f32_16x16x32_bf16(a1, b, acc1[1][j], 0, 0, 0);
            }
        }
        __syncthreads();                       // chunk c consumed
        if (c + 1 < 8) {
            unsigned short t[8] = {f2bf(q0.x), f2bf(q0.y), f2bf(q0.z), f2bf(q0.w),
                                   f2bf(q1.x), f2bf(q1.y), f2bf(q1.z), f2bf(q1.w)};
            *(uint4*)&lds[OFF_MISC + ((c + 1) & 1) * STG_BUF + srow * LD_STG + skl] = *(uint4*)t;
        } else {
            // chunk 8 (k 512..543): bounds then zeros -> buf0
            const int frow = tid >> 3;
            const int fkl  = (tid & 7) * 4;
            unsigned short t[4];
            #pragma unroll
            for (int i = 0; i < 4; ++i) {
                const int gk = 512 + fkl + i;
                t[i] = (gk < 516) ? f2bf(bounds[gk - 512]) : (unsigned short)0;
            }
            *(uint2*)&lds[OFF_MISC + frow * LD_STG + fkl] = *(uint2*)t;
        }
    }
    __syncthreads();
    // chunk 8: single k-step (ks index 16)
    {
        const bf16x8 a0 = *(const bf16x8*)&lds[OFF_MISC + (mrow + m_l     ) * LD_STG + quad*8];
        const bf16x8 a1 = *(const bf16x8*)&lds[OFF_MISC + (mrow + m_l + 16) * LD_STG + quad*8];
        #pragma unroll
        for (int j = 0; j < 8; ++j) {
            const bf16x8 b = *(const bf16x8*)(W1l + (size_t)(j * 17 + 16) * 512);
            acc1[0][j] = __builtin_amdgcn_mfma_f32_16x16x32_bf16(a0, b, acc1[0][j], 0, 0, 0);
            acc1[1][j] = __builtin_amdgcn_mfma_f32_16x16x32_bf16(a1, b, acc1[1][j], 0, 0, 0);
        }
    }
    // L1 epilogue -> h1
    #pragma unroll
    for (int j = 0; j < 8; ++j) {
        const int col = wn*128 + j*16 + m_l;
        const float bv = c1[col];
        #pragma unroll
        for (int i = 0; i < 2; ++i)
            #pragma unroll
            for (int r = 0; r < 4; ++r) {
                float v = acc1[i][j][r] + bv;
                v = v > 0.f ? v : 0.2f * v;
                lds[OFF_H1 + (mrow + i*16 + quad*4 + r) * LD_H1 + col] = f2bf(v);
            }
    }
    __syncthreads();

    // ---------------- Layers 2-4 (LDS-resident) -----------------------------
    layer_gemm<4,16>(lds, OFF_H1,   LD_H1, OFF_MISC, LD_H2, Wt2, c2, wn, mrow, lane);
    __syncthreads();
    layer_gemm<2,8 >(lds, OFF_MISC, LD_H2, OFF_H3,   LD_H3, Wt3, c3, wn, mrow, lane);
    __syncthreads();
    layer_gemm<1,4 >(lds, OFF_H3,   LD_H3, OFF_MISC, LD_H4, Wt4, c4, wn, mrow, lane);
    __syncthreads();

    // ---------------- Layer 5 (64->256 fp32) + QP ---------------------------
    const float4 bnd = *(const float4*)bounds;
    const float4 cc  = ((const float4*)c5)[lane];
    float ax[8], ay[8], aw[8], ah[8];
    #pragma unroll
    for (int r = 0; r < 8; ++r) { ax[r] = cc.x; ay[r] = cc.y; aw[r] = cc.z; ah[r] = cc.w; }
    const float4* __restrict__ W5v = (const float4*)W5;   // [k][64 objs]
    const int rbase = wid * 8;                            // 8 waves x 8 rows = 64

    #pragma unroll 2
    for (int k4 = 0; k4 < 64; k4 += 4) {
        unsigned short hs[8][4];
        #pragma unroll
        for (int r = 0; r < 8; ++r) {
            const ushort4 t = *(const ushort4*)&lds[OFF_MISC + (rbase + r) * LD_H4 + k4];
            hs[r][0] = t.x; hs[r][1] = t.y; hs[r][2] = t.z; hs[r][3] = t.w;
        }
        #pragma unroll
        for (int kk = 0; kk < 4; ++kk) {
            const float4 w = W5v[(size_t)(k4 + kk) * 64 + lane];
            #pragma unroll
            for (int r = 0; r < 8; ++r) {
                const float h = bf2f(hs[r][kk]);
                ax[r] = fmaf(h, w.x, ax[r]);
                ay[r] = fmaf(h, w.y, ay[r]);
                aw[r] = fmaf(h, w.z, aw[r]);
                ah[r] = fmaf(h, w.w, ah[r]);
            }
        }
    }

    const float b0 = bnd.x, b1 = bnd.y, b2 = bnd.z, b3 = bnd.w;
    #pragma unroll
    for (int r = 0; r < 8; ++r) {
        float xs, wo, ys, ho;
        {
            const float px = ax[r], pw = aw[r];
            const float x0 = fmaxf(px, b0);
            const float g0 = fmaxf(pw, 1.0f);
            const float t  = 0.5f * (b2 - px - pw);
            const float xl = fminf(fmaxf(px + t, b0), b2 - 1.0f);
            const bool over = (x0 + g0) > b2;
            const float x = over ? xl : x0;
            const float g = over ? (b2 - xl) : g0;
            xs = x; wo = x + g;
        }
        {
            const float py = ay[r], ph = ah[r];
            const float x0 = fmaxf(py, b1);
            const float g0 = fmaxf(ph, 1.0f);
            const float t  = 0.5f * (b3 - py - ph);
            const float xl = fminf(fmaxf(py + t, b1), b3 - 1.0f);
            const bool over = (x0 + g0) > b3;
            const float x = over ? xl : x0;
            const float g = over ? (b3 - xl) : g0;
            ys = x; ho = x + g;
        }
        float4 o; o.x = xs; o.y = ys; o.z = wo; o.w = ho;
        ((float4*)out)[(size_t)(bm + rbase + r) * 64 + lane] = o;
    }
}

extern "C" void kernel_launch(void* const* d_in, const int* in_sizes, int n_in,
                              void* d_out, int out_size, void* d_ws, size_t ws_size,
                              hipStream_t stream) {
    const float* z      = (const float*)d_in[0];
    const float* bounds = (const float*)d_in[1];
    const float* W1 = (const float*)d_in[2];
    const float* c1 = (const float*)d_in[3];
    const float* W2 = (const float*)d_in[4];
    const float* c2 = (const float*)d_in[5];
    const float* W3 = (const float*)d_in[6];
    const float* c3 = (const float*)d_in[7];
    const float* W4 = (const float*)d_in[8];
    const float* c4 = (const float*)d_in[9];
    const float* W5 = (const float*)d_in[10];
    const float* c5 = (const float*)d_in[11];
    float* out = (float*)d_out;

    unsigned short* ws  = (unsigned short*)d_ws;
    unsigned short* Wt1 = ws;               // 512x544 = 278528
    unsigned short* Wt2 = Wt1 + 278528;     // 256x512 = 131072
    unsigned short* Wt3 = Wt2 + 131072;     // 128x256 = 32768
    unsigned short* Wt4 = Wt3 + 32768;      //  64x128 =  8192

    pack_wt<<<dim3(1088, 4), 256, 0, stream>>>(W1, Wt1, W2, Wt2, W3, Wt3, W4, Wt4);
    fused_mlp_qp<<<dim3(MROWS / 64), 512, 0, stream>>>(
        z, bounds, Wt1, c1, Wt2, c2, Wt3, c3, Wt4, c4, W5, c5, out);
}

// Round 7
// 133.458 us; speedup vs baseline: 1.1123x; 1.0515x over previous
//
#include <hip/hip_runtime.h>

// ---------------------------------------------------------------------------
// CVX_Reasoning_Engine — Round 7: barrier-minimal fused kernel.
//   __syncthreads drains vmcnt(0) on gfx950, so R4/R6's intra-L1 prefetch
//   was structurally defeated (each of ~17 barriers exposed full latency).
//   Fix: stage ALL of z into LDS once, then 5 uniform barrier-free MFMA
//   layers + QP tail. 6 barriers total. 32 rows/block, 512 blocks, 2/CU.
// ---------------------------------------------------------------------------

#define MROWS 16384

typedef __attribute__((ext_vector_type(8))) short bf16x8;   // 8 bf16 = 4 VGPRs
typedef __attribute__((ext_vector_type(4))) float floatx4;

__device__ __forceinline__ unsigned short f2bf(float x) {
    union { float f; unsigned u; } c; c.f = x;
    unsigned r = c.u + 0x7fffu + ((c.u >> 16) & 1u);   // RNE
    return (unsigned short)(r >> 16);
}
__device__ __forceinline__ float bf2f(unsigned short b) {
    union { unsigned u; float f; } c; c.u = ((unsigned)b) << 16;
    return c.f;
}

// ---- pack W (KxN fp32) -> fragment-ordered bf16 ----------------------------
// T[((ntile*KS + ks)*64 + lane)*8 + e] = W[k][n],  n = ntile*16 + (lane&15),
// k = ks*32 + (lane>>4)*8 + e.  Reads coalesced (idx = k*N + n, n fastest).
__global__ __launch_bounds__(256) void pack_wt(
    const float* __restrict__ W1, unsigned short* __restrict__ T1,
    const float* __restrict__ W2, unsigned short* __restrict__ T2,
    const float* __restrict__ W3, unsigned short* __restrict__ T3,
    const float* __restrict__ W4, unsigned short* __restrict__ T4)
{
    const float* W; unsigned short* T; int Kreal, KS, nshift;
    switch (blockIdx.y) {
        case 0:  W = W1; T = T1; Kreal = 516; KS = 17; nshift = 9; break;
        case 1:  W = W2; T = T2; Kreal = 512; KS = 16; nshift = 8; break;
        case 2:  W = W3; T = T3; Kreal = 256; KS = 8;  nshift = 7; break;
        default: W = W4; T = T4; Kreal = 128; KS = 4;  nshift = 6; break;
    }
    const int N = 1 << nshift;
    const int idx = blockIdx.x * 256 + threadIdx.x;   // k*N + n over padded K
    if (idx >= N * KS * 32) return;
    const int k = idx >> nshift;
    const int n = idx & (N - 1);
    const unsigned short v = (k < Kreal) ? f2bf(W[idx]) : (unsigned short)0;
    const int ntile = n >> 4, m_l = n & 15;
    const int ks = k >> 5, quad = (k >> 3) & 3, e = k & 7;
    T[(size_t)(((ntile * KS + ks) * 64) + quad * 16 + m_l) * 8 + e] = v;
}

// ---- LDS layout (ushort element offsets) -----------------------------------
// Region A: zs 32x552 @0 (cols 512..515 = bounds, 516..551 = 0).
//           After L1: h2 32x264 @0, h4 32x72 @8448 overlay zs.
// Region B: h1 32x520 @17664. After L2: h3 32x136 @17664 overlays h1.
// Total 34,304 us = 68,608 B -> 2 blocks/CU.
// Bank math (dwords mod 32): zs stride 552us=138dw==10 -> rows spread, ~2-way;
// h1 520us=130dw==2; h2 264us=66dw==2; h3 136us=34dw==2; h4 72us=18dw==18. OK.
#define OFF_ZS   0
#define LD_ZS    552
#define OFF_H1   17664
#define LD_H1    520
#define OFF_H2   0
#define LD_H2    264
#define OFF_H3   17664
#define LD_H3    136
#define OFF_H4   8448
#define LD_H4    72
#define LDS_TOT  34304

// generic MFMA layer: C[32xN] = lrelu(A[32xK] @ W^T + bias), barrier-free.
// Wt fragment-ordered; 4 waves split N; wave tile 32 x (NF*16).
// Plain loop body — compiler schedules loads (R5: manual prefetch loses).
template<int NF, int KSTEPS>
__device__ __forceinline__ void layer_gemm(
    unsigned short* lds, int offA, int lda, int offC, int ldc,
    const unsigned short* __restrict__ Wt,
    const float* __restrict__ bias, int wid, int lane)
{
    const int m_l = lane & 15, quad = lane >> 4;
    const unsigned short* __restrict__ Wl =
        Wt + ((size_t)(wid * NF) * KSTEPS * 64 + lane) * 8;
    floatx4 acc[2][NF];
    #pragma unroll
    for (int i = 0; i < 2; ++i)
        #pragma unroll
        for (int j = 0; j < NF; ++j)
            acc[i][j] = (floatx4){0.f, 0.f, 0.f, 0.f};

    #pragma unroll
    for (int ks = 0; ks < KSTEPS; ++ks) {
        const bf16x8 a0 = *(const bf16x8*)&lds[offA + (m_l     ) * lda + ks*32 + quad*8];
        const bf16x8 a1 = *(const bf16x8*)&lds[offA + (m_l + 16) * lda + ks*32 + quad*8];
        #pragma unroll
        for (int j = 0; j < NF; ++j) {
            const bf16x8 b = *(const bf16x8*)(Wl + (size_t)(j * KSTEPS + ks) * 512);
            acc[0][j] = __builtin_amdgcn_mfma_f32_16x16x32_bf16(a0, b, acc[0][j], 0, 0, 0);
            acc[1][j] = __builtin_amdgcn_mfma_f32_16x16x32_bf16(a1, b, acc[1][j], 0, 0, 0);
        }
    }
    // epilogue: bias + lrelu -> bf16 LDS. C/D: col=lane&15, row=quad*4+r.
    #pragma unroll
    for (int j = 0; j < NF; ++j) {
        const int col = wid * (NF * 16) + j * 16 + m_l;
        const float bv = bias[col];
        #pragma unroll
        for (int i = 0; i < 2; ++i)
            #pragma unroll
            for (int r = 0; r < 4; ++r) {
                float v = acc[i][j][r] + bv;
                v = v > 0.f ? v : 0.2f * v;
                lds[offC + (i*16 + quad*4 + r) * ldc + col] = f2bf(v);
            }
    }
}

__global__ __launch_bounds__(256, 2) void fused_mlp_qp(
    const float* __restrict__ z, const float* __restrict__ bounds,
    const unsigned short* __restrict__ Wt1, const float* __restrict__ c1,
    const unsigned short* __restrict__ Wt2, const float* __restrict__ c2,
    const unsigned short* __restrict__ Wt3, const float* __restrict__ c3,
    const unsigned short* __restrict__ Wt4, const float* __restrict__ c4,
    const float* __restrict__ W5, const float* __restrict__ c5,
    float* __restrict__ out)
{
    __shared__ unsigned short lds[LDS_TOT];
    const int tid  = threadIdx.x;
    const int wid  = tid >> 6, lane = tid & 63;
    const int bm   = blockIdx.x * 32;

    const float4 bnd = *(const float4*)bounds;

    // ---- stage ALL of z for this block (one latency, then barrier) ---------
    {
        const float4* __restrict__ zf = (const float4*)(z + (size_t)bm * 512);
        #pragma unroll
        for (int i = 0; i < 16; ++i) {
            const int f   = i * 256 + tid;          // float4 idx in 32x128
            const int row = f >> 7, c4 = f & 127;
            const float4 v = zf[f];
            unsigned short t4[4] = {f2bf(v.x), f2bf(v.y), f2bf(v.z), f2bf(v.w)};
            *(uint2*)&lds[OFF_ZS + row * LD_ZS + c4 * 4] = *(uint2*)t4;
        }
        // tail cols 512..551: bounds then zeros (5 x 8-ushort chunks per row)
        if (tid < 160) {
            const int row = tid / 5, j = tid % 5;
            unsigned short t8[8] = {0,0,0,0,0,0,0,0};
            if (j == 0) { t8[0] = f2bf(bnd.x); t8[1] = f2bf(bnd.y);
                          t8[2] = f2bf(bnd.z); t8[3] = f2bf(bnd.w); }
            *(uint4*)&lds[OFF_ZS + row * LD_ZS + 512 + j * 8] = *(uint4*)t8;
        }
    }
    __syncthreads();

    // ---- 4 uniform barrier-free MFMA layers --------------------------------
    layer_gemm<8,17>(lds, OFF_ZS, LD_ZS, OFF_H1, LD_H1, Wt1, c1, wid, lane);
    __syncthreads();
    layer_gemm<4,16>(lds, OFF_H1, LD_H1, OFF_H2, LD_H2, Wt2, c2, wid, lane);
    __syncthreads();
    layer_gemm<2,8 >(lds, OFF_H2, LD_H2, OFF_H3, LD_H3, Wt3, c3, wid, lane);
    __syncthreads();
    layer_gemm<1,4 >(lds, OFF_H3, LD_H3, OFF_H4, LD_H4, Wt4, c4, wid, lane);
    __syncthreads();

    // ---------------- Layer 5 (64->256 fp32) + QP ---------------------------
    const float4 cc = ((const float4*)c5)[lane];
    float ax[8], ay[8], aw[8], ah[8];
    #pragma unroll
    for (int r = 0; r < 8; ++r) { ax[r] = cc.x; ay[r] = cc.y; aw[r] = cc.z; ah[r] = cc.w; }
    const float4* __restrict__ W5v = (const float4*)W5;   // [k][64 objs]
    const int rbase = wid * 8;                            // 4 waves x 8 rows

    #pragma unroll 2
    for (int k4 = 0; k4 < 64; k4 += 4) {
        unsigned short hs[8][4];
        #pragma unroll
        for (int r = 0; r < 8; ++r) {
            const ushort4 t = *(const ushort4*)&lds[OFF_H4 + (rbase + r) * LD_H4 + k4];
            hs[r][0] = t.x; hs[r][1] = t.y; hs[r][2] = t.z; hs[r][3] = t.w;
        }
        #pragma unroll
        for (int kk = 0; kk < 4; ++kk) {
            const float4 w = W5v[(size_t)(k4 + kk) * 64 + lane];
            #pragma unroll
            for (int r = 0; r < 8; ++r) {
                const float h = bf2f(hs[r][kk]);
                ax[r] = fmaf(h, w.x, ax[r]);
                ay[r] = fmaf(h, w.y, ay[r]);
                aw[r] = fmaf(h, w.z, aw[r]);
                ah[r] = fmaf(h, w.w, ah[r]);
            }
        }
    }

    const float b0 = bnd.x, b1 = bnd.y, b2 = bnd.z, b3 = bnd.w;
    #pragma unroll
    for (int r = 0; r < 8; ++r) {
        float xs, wo, ys, ho;
        {
            const float px = ax[r], pw = aw[r];
            const float x0 = fmaxf(px, b0);
            const float g0 = fmaxf(pw, 1.0f);
            const float t  = 0.5f * (b2 - px - pw);
            const float xl = fminf(fmaxf(px + t, b0), b2 - 1.0f);
            const bool over = (x0 + g0) > b2;
            const float x = over ? xl : x0;
            const float g = over ? (b2 - xl) : g0;
            xs = x; wo = x + g;
        }
        {
            const float py = ay[r], ph = ah[r];
            const float x0 = fmaxf(py, b1);
            const float g0 = fmaxf(ph, 1.0f);
            const float t  = 0.5f * (b3 - py - ph);
            const float xl = fminf(fmaxf(py + t, b1), b3 - 1.0f);
            const bool over = (x0 + g0) > b3;
            const float x = over ? xl : x0;
            const float g = over ? (b3 - xl) : g0;
            ys = x; ho = x + g;
        }
        float4 o; o.x = xs; o.y = ys; o.z = wo; o.w = ho;
        ((float4*)out)[(size_t)(bm + rbase + r) * 64 + lane] = o;
    }
}

extern "C" void kernel_launch(void* const* d_in, const int* in_sizes, int n_in,
                              void* d_out, int out_size, void* d_ws, size_t ws_size,
                              hipStream_t stream) {
    const float* z      = (const float*)d_in[0];
    const float* bounds = (const float*)d_in[1];
    const float* W1 = (const float*)d_in[2];
    const float* c1 = (const float*)d_in[3];
    const float* W2 = (const float*)d_in[4];
    const float* c2 = (const float*)d_in[5];
    const float* W3 = (const float*)d_in[6];
    const float* c3 = (const float*)d_in[7];
    const float* W4 = (const float*)d_in[8];
    const float* c4 = (const float*)d_in[9];
    const float* W5 = (const float*)d_in[10];
    const float* c5 = (const float*)d_in[11];
    float* out = (float*)d_out;

    unsigned short* ws  = (unsigned short*)d_ws;
    unsigned short* Wt1 = ws;               // 512x544 = 278528
    unsigned short* Wt2 = Wt1 + 278528;     // 256x512 = 131072
    unsigned short* Wt3 = Wt2 + 131072;     // 128x256 = 32768
    unsigned short* Wt4 = Wt3 + 32768;      //  64x128 =  8192

    pack_wt<<<dim3(1088, 4), 256, 0, stream>>>(W1, Wt1, W2, Wt2, W3, Wt3, W4, Wt4);
    fused_mlp_qp<<<dim3(MROWS / 32), 256, 0, stream>>>(
        z, bounds, Wt1, c1, Wt2, c2, Wt3, c3, Wt4, c4, W5, c5, out);
}